// Round 1
// baseline (78.550 us; speedup 1.0000x reference)
//
#include <hip/hip_runtime.h>

#define TILE 32
#define INT_ 70   // 2*TILE + 6 halo (filter len 8, stride 2)

__device__ __forceinline__ int refl(int i, int n) {
    i = (i < 0) ? (-i - 1) : i;
    i = (i >= n) ? (2 * n - 1 - i) : i;
    return i;
}

// Fused one-level 2D DWT: out[i] = sum_k f[k] * ext[2i+1-k], symmetric ext.
// oA = lo_w,lo_h ; oH = lo_w,hi_h ; oV = hi_w,lo_h ; oD = hi_w,hi_h
__global__ __launch_bounds__(256, 4)
void dwt2_fused(const float* __restrict__ in, int n, int m,
                float* __restrict__ oA, float* __restrict__ oH,
                float* __restrict__ oV, float* __restrict__ oD)
{
    constexpr float LOF[8] = {
        -0.010597401784997278f,  0.032883011666982945f,
         0.030841381835986965f, -0.18703481171888114f,
        -0.02798376941698385f,   0.6308807679295904f,
         0.7148465705525415f,    0.23037781330885523f };
    constexpr float HIF[8] = {
        -0.23037781330885523f,   0.7148465705525415f,
        -0.6308807679295904f,   -0.02798376941698385f,
         0.18703481171888114f,   0.030841381835986965f,
        -0.032883011666982945f, -0.010597401784997278f };

    __shared__ float s_in[INT_][INT_ + 2];   // 70 x 72 (pad)
    __shared__ float s_lo[INT_][TILE + 1];   // 70 x 33
    __shared__ float s_hi[INT_][TILE + 1];

    const int tid = threadIdx.x;
    const int c0 = blockIdx.x * TILE;
    const int r0 = blockIdx.y * TILE;
    const int b  = blockIdx.z;
    const float* a = in + (size_t)b * n * n;

    const int rb = 2 * r0 - 6;   // tile row t -> global row rb + t (pre-reflect)
    const int cb = 2 * c0 - 6;

    // Stage input tile with symmetric reflection folded into the load.
    for (int idx = tid; idx < INT_ * INT_; idx += 256) {
        int tr = idx / INT_, tc = idx - tr * INT_;
        s_in[tr][tc] = a[(size_t)refl(rb + tr, n) * n + refl(cb + tc, n)];
    }
    __syncthreads();

    // Horizontal pass: lo/hi for all 70 halo rows, 32 output cols.
    // needed input tile col for output col c, tap k: t = 2c + 7 - k  (0..69)
    for (int idx = tid; idx < INT_ * TILE; idx += 256) {
        int tr = idx >> 5, c = idx & 31;
        float lo = 0.f, hi = 0.f;
        #pragma unroll
        for (int k = 0; k < 8; ++k) {
            float v = s_in[tr][2 * c + 7 - k];
            lo += LOF[k] * v;
            hi += HIF[k] * v;
        }
        s_lo[tr][c] = lo;
        s_hi[tr][c] = hi;
    }
    __syncthreads();

    // Vertical pass: 32x32 outputs, 4 subbands each.
    for (int idx = tid; idx < TILE * TILE; idx += 256) {
        int r = idx >> 5, c = idx & 31;
        int gr = r0 + r, gc = c0 + c;
        if (gr >= m || gc >= m) continue;
        float A = 0.f, H = 0.f, V = 0.f, D = 0.f;
        #pragma unroll
        for (int k = 0; k < 8; ++k) {
            float l = s_lo[2 * r + 7 - k][c];
            float h = s_hi[2 * r + 7 - k][c];
            A += LOF[k] * l;
            H += HIF[k] * l;
            V += LOF[k] * h;
            D += HIF[k] * h;
        }
        size_t o = (size_t)b * m * m + (size_t)gr * m + gc;
        oA[o] = A; oH[o] = H; oV[o] = V; oD[o] = D;
    }
}

extern "C" void kernel_launch(void* const* d_in, const int* in_sizes, int n_in,
                              void* d_out, int out_size, void* d_ws, size_t ws_size,
                              hipStream_t stream) {
    const float* x = (const float*)d_in[0];
    float* out = (float*)d_out;
    float* ws  = (float*)d_ws;

    const int B = 16;
    const int n1 = 1024, m1 = 515;   // (1024+7)/2
    const int n2 = 515,  m2 = 261;   // (515+7)/2
    const int n3 = 261,  m3 = 134;   // (261+7)/2

    const size_t sz1 = (size_t)B * m1 * m1;  // 4,243,600
    const size_t sz2 = (size_t)B * m2 * m2;  // 1,089,936
    const size_t sz3 = (size_t)B * m3 * m3;  //   287,296

    // workspace: cA chain
    float* a1 = ws;
    float* a2 = ws + sz1;

    // d_out layout: a3, lh3, hl3, hh3, lh2, hl2, hh2, lh1, hl1, hh1
    float* a3  = out;
    float* lh3 = a3  + sz3;
    float* hl3 = lh3 + sz3;
    float* hh3 = hl3 + sz3;
    float* lh2 = hh3 + sz3;
    float* hl2 = lh2 + sz2;
    float* hh2 = hl2 + sz2;
    float* lh1 = hh2 + sz2;
    float* hl1 = lh1 + sz1;
    float* hh1 = hl1 + sz1;

    dim3 blk(256);
    dim3 g1((m1 + TILE - 1) / TILE, (m1 + TILE - 1) / TILE, B);
    dim3 g2((m2 + TILE - 1) / TILE, (m2 + TILE - 1) / TILE, B);
    dim3 g3((m3 + TILE - 1) / TILE, (m3 + TILE - 1) / TILE, B);

    dwt2_fused<<<g1, blk, 0, stream>>>(x,  n1, m1, a1, lh1, hl1, hh1);
    dwt2_fused<<<g2, blk, 0, stream>>>(a1, n2, m2, a2, lh2, hl2, hh2);
    dwt2_fused<<<g3, blk, 0, stream>>>(a2, n3, m3, a3, lh3, hl3, hh3);
}

// Round 2
// 66.805 us; speedup vs baseline: 1.1758x; 1.1758x over previous
//
#include <hip/hip_runtime.h>

#define NT 256

__device__ __forceinline__ int refl(int i, int n) {
    i = (i < 0) ? (-i - 1) : i;
    i = (i >= n) ? (2 * n - 1 - i) : i;
    return i;
}

// One fused 2D DWT level. Tile: 32x32 outputs per block.
// Phase A: global -> horizontal lo/hi conv -> LDS (transposed, (lo,hi) interleaved)
// Phase B: vertical conv from LDS -> 4 subbands.
// s[c][t][0/1]: c = output col within tile (0..31), t = halo row (0..69, pitch 78).
__global__ __launch_bounds__(256, 8)
void dwt2_fused(const float* __restrict__ in, int n, long long ldin, long long inb,
                int m,
                float* __restrict__ oA, long long ldA, long long Ab,
                float* __restrict__ oH, float* __restrict__ oV, float* __restrict__ oD)
{
    constexpr float LOF[8] = {
        -0.010597401784997278f,  0.032883011666982945f,
         0.030841381835986965f, -0.18703481171888114f,
        -0.02798376941698385f,   0.6308807679295904f,
         0.7148465705525415f,    0.23037781330885523f };
    constexpr float HIF[8] = {
        -0.23037781330885523f,   0.7148465705525415f,
        -0.6308807679295904f,   -0.02798376941698385f,
         0.18703481171888114f,   0.030841381835986965f,
        -0.032883011666982945f, -0.010597401784997278f };

    __shared__ float s[32][78][2];   // 19968 B

    const int tid = threadIdx.x;
    const int bx = blockIdx.x, by = blockIdx.y, b = blockIdx.z;
    const int c0 = bx * 32, r0 = by * 32;
    const float* Ain = in + (long long)b * inb;

    const int rb = 2 * r0 - 6;       // LDS row t <-> input row rb + t
    const int cbase = 2 * c0 - 8;    // pair pc window: cols cbase+4pc .. +11

    const bool interior = (rb >= 0) && (rb + 69 < n) && (cbase >= 0) && (cbase + 71 < n);

    // ---- Phase A: 70 rows x 16 col-pairs ----
    if (interior) {
        for (int idx = tid; idx < 70 * 16; idx += NT) {
            const int tr = idx >> 4, pc = idx & 15;
            const float4* p = (const float4*)(Ain + (long long)(rb + tr) * ldin + (cbase + 4 * pc));
            float4 a0 = p[0], a1 = p[1], a2 = p[2];
            float v[12] = { a0.x, a0.y, a0.z, a0.w,
                            a1.x, a1.y, a1.z, a1.w,
                            a2.x, a2.y, a2.z, a2.w };
            float lo0 = 0.f, hi0 = 0.f, lo1 = 0.f, hi1 = 0.f;
            #pragma unroll
            for (int k = 0; k < 8; ++k) {
                lo0 += LOF[k] * v[9 - k];  hi0 += HIF[k] * v[9 - k];
                lo1 += LOF[k] * v[11 - k]; hi1 += HIF[k] * v[11 - k];
            }
            const int c = 2 * pc;
            *(float2*)&s[c][tr][0]     = make_float2(lo0, hi0);
            *(float2*)&s[c + 1][tr][0] = make_float2(lo1, hi1);
        }
    } else {
        for (int idx = tid; idx < 70 * 16; idx += NT) {
            const int tr = idx >> 4, pc = idx & 15;
            const float* row = Ain + (long long)refl(rb + tr, n) * ldin;
            const int cw = cbase + 4 * pc;
            float v[12];
            v[0] = 0.f; v[1] = 0.f;
            #pragma unroll
            for (int u = 2; u < 12; ++u) v[u] = row[refl(cw + u, n)];
            float lo0 = 0.f, hi0 = 0.f, lo1 = 0.f, hi1 = 0.f;
            #pragma unroll
            for (int k = 0; k < 8; ++k) {
                lo0 += LOF[k] * v[9 - k];  hi0 += HIF[k] * v[9 - k];
                lo1 += LOF[k] * v[11 - k]; hi1 += HIF[k] * v[11 - k];
            }
            const int c = 2 * pc;
            *(float2*)&s[c][tr][0]     = make_float2(lo0, hi0);
            *(float2*)&s[c + 1][tr][0] = make_float2(lo1, hi1);
        }
    }
    __syncthreads();

    // ---- Phase B: 32 cols x 16 row-pairs ----
    for (int idx = tid; idx < 512; idx += NT) {
        const int c = idx & 31, pr = idx >> 5;
        const float4* q = (const float4*)&s[c][4 * pr][0];
        float lo[12], hi[12];
        #pragma unroll
        for (int i = 0; i < 6; ++i) {
            float4 t = q[i];
            lo[2 * i] = t.x;  hi[2 * i] = t.y;
            lo[2 * i + 1] = t.z;  hi[2 * i + 1] = t.w;
        }
        float A0 = 0.f, H0 = 0.f, V0 = 0.f, D0 = 0.f;
        float A1 = 0.f, H1 = 0.f, V1 = 0.f, D1 = 0.f;
        #pragma unroll
        for (int k = 0; k < 8; ++k) {
            float l0 = lo[7 - k], h0 = hi[7 - k];
            float l1 = lo[9 - k], h1 = hi[9 - k];
            A0 += LOF[k] * l0;  H0 += HIF[k] * l0;
            V0 += LOF[k] * h0;  D0 += HIF[k] * h0;
            A1 += LOF[k] * l1;  H1 += HIF[k] * l1;
            V1 += LOF[k] * h1;  D1 += HIF[k] * h1;
        }
        const int gr = r0 + 2 * pr, gc = c0 + c;
        if (gc < m) {
            const long long ob = (long long)b * m * m + (long long)gr * m + gc;
            if (gr < m) {
                oA[(long long)b * Ab + (long long)gr * ldA + gc] = A0;
                oH[ob] = H0; oV[ob] = V0; oD[ob] = D0;
            }
            if (gr + 1 < m) {
                oA[(long long)b * Ab + (long long)(gr + 1) * ldA + gc] = A1;
                oH[ob + m] = H1; oV[ob + m] = V1; oD[ob + m] = D1;
            }
        }
    }
}

extern "C" void kernel_launch(void* const* d_in, const int* in_sizes, int n_in,
                              void* d_out, int out_size, void* d_ws, size_t ws_size,
                              hipStream_t stream) {
    const float* x = (const float*)d_in[0];
    float* out = (float*)d_out;
    float* ws  = (float*)d_ws;

    const int B = 16;
    const int n1 = 1024, m1 = 515;
    const int n2 = 515,  m2 = 261;
    const int n3 = 261,  m3 = 134;

    // padded cA intermediates (16B-aligned rows)
    const long long ld1 = 516, b1 = (long long)m1 * ld1;   // 265,740
    const long long ld2 = 264, b2 = (long long)m2 * ld2;   //  68,904
    float* a1 = ws;
    float* a2 = ws + (size_t)(b1 * B);                     // 4,251,840 floats in

    const size_t sz1 = (size_t)B * m1 * m1;
    const size_t sz2 = (size_t)B * m2 * m2;
    const size_t sz3 = (size_t)B * m3 * m3;

    // d_out: a3, lh3, hl3, hh3, lh2, hl2, hh2, lh1, hl1, hh1
    float* a3  = out;
    float* lh3 = a3  + sz3;
    float* hl3 = lh3 + sz3;
    float* hh3 = hl3 + sz3;
    float* lh2 = hh3 + sz3;
    float* hl2 = lh2 + sz2;
    float* hh2 = hl2 + sz2;
    float* lh1 = hh2 + sz2;
    float* hl1 = lh1 + sz1;
    float* hh1 = hl1 + sz1;

    dim3 blk(NT);
    dim3 g1((m1 + 31) / 32, (m1 + 31) / 32, B);
    dim3 g2((m2 + 31) / 32, (m2 + 31) / 32, B);
    dim3 g3((m3 + 31) / 32, (m3 + 31) / 32, B);

    dwt2_fused<<<g1, blk, 0, stream>>>(x,  n1, 1024, (long long)n1 * n1,
                                       m1, a1, ld1, b1, lh1, hl1, hh1);
    dwt2_fused<<<g2, blk, 0, stream>>>(a1, n2, ld1, b1,
                                       m2, a2, ld2, b2, lh2, hl2, hh2);
    dwt2_fused<<<g3, blk, 0, stream>>>(a2, n3, ld2, b2,
                                       m3, (float*)(out), m3, (long long)m3 * m3, lh3, hl3, hh3);
}